// Round 8
// baseline (229.318 us; speedup 1.0000x reference)
//
#include <hip/hip_runtime.h>
#include <stdint.h>

typedef __bf16 bf16_t;
typedef bf16_t bf16x8 __attribute__((ext_vector_type(8)));
typedef float f32x4 __attribute__((ext_vector_type(4)));
typedef unsigned short us8 __attribute__((ext_vector_type(8)));
typedef unsigned short us4 __attribute__((ext_vector_type(4)));
typedef unsigned int u32x4 __attribute__((ext_vector_type(4)));

#define B_ 4
#define T_ 4096
#define C_ 1024
#define D_ 128

#define NCHUNK_PB 272   // per batch: sum over 32 q-tiles(128 rows) of ceil((2jt2+2)/4)
#define QSCALE 0.12751744f  // (1/sqrt(128)) * log2(e), folded into Q
#define M0 14.0f            // fixed softmax base (log2 domain); cancels in combine

__device__ __forceinline__ uint16_t f2bf(float f) {
    union { float f; uint32_t u; } v; v.f = f;
    uint32_t u = v.u;
    uint32_t r = (u + 0x7fffu + ((u >> 16) & 1u)) >> 16;
    return (uint16_t)r;
}

// round-half-up bf16 (2 VALU)
__device__ __forceinline__ uint16_t bfru(float f) {
    return (uint16_t)((__float_as_uint(f) + 0x8000u) >> 16);
}

__device__ __forceinline__ float bf2f(uint16_t u) {
    return __uint_as_float((uint32_t)u << 16);
}

// ---------------------------------------------------------------------------
// Kernel 1: W[C,D] fp32 -> WT[w][n][k] bf16 (transposed), w in {q,k,v}
// ---------------------------------------------------------------------------
__global__ __launch_bounds__(256) void prep_w(const float* __restrict__ Wq,
                                              const float* __restrict__ Wk,
                                              const float* __restrict__ Wv,
                                              uint16_t* __restrict__ WT) {
    int idx = blockIdx.x * 256 + threadIdx.x;
    if (idx >= 3 * D_ * C_) return;
    int w   = idx / (D_ * C_);
    int rem = idx - w * (D_ * C_);
    int n   = rem / C_;
    int k   = rem - n * C_;
    const float* W = (w == 0) ? Wq : (w == 1) ? Wk : Wv;
    WT[idx] = f2bf(W[(size_t)k * D_ + n]);
}

// ---------------------------------------------------------------------------
// Kernel 2: QKV projection (unchanged R7). grid = 3 W x 256 M-tiles(64 rows).
// BK=64. Q gets QSCALE folded in.
// ---------------------------------------------------------------------------
#define GST 72   // 64+8 elems leading-dim pad

__global__ __launch_bounds__(256) void qkv_gemm(const float* __restrict__ x,
                                                const uint16_t* __restrict__ WT,
                                                uint16_t* __restrict__ qb,
                                                uint16_t* __restrict__ kb,
                                                uint16_t* __restrict__ vT) {
    __shared__ __align__(16) uint16_t A_lds[64 * GST];
    __shared__ __align__(16) uint16_t W_lds[128 * GST];

    int tid  = threadIdx.x;
    int lane = tid & 63;
    int wave = tid >> 6;
    int quad = lane >> 4;
    int lx   = lane & 15;
    int wm   = wave >> 1, wn = wave & 1;

    int bx   = blockIdx.x;
    int wsel = bx % 3;
    int m0   = (bx / 3) * 64;
    const uint16_t* Wp = WT + (size_t)wsel * (D_ * C_);

    f32x4 acc[2][4];
    for (int mf = 0; mf < 2; mf++)
        for (int nf = 0; nf < 4; nf++)
            acc[mf][nf] = (f32x4){0.f, 0.f, 0.f, 0.f};

    int arow = tid >> 2, acb = (tid & 3) * 16;  // A: 16 floats/thread
    int wrow = tid >> 1, wcb = (tid & 1) * 32;  // W: 32 bf16/thread

    for (int k0 = 0; k0 < C_; k0 += 64) {
        {
            const float* xp = x + (size_t)(m0 + arow) * C_ + k0 + acb;
            uint32_t d[8];
#pragma unroll
            for (int j = 0; j < 4; j++) {
                float4 f = *(const float4*)(xp + j * 4);
                uint32_t u0 = __float_as_uint(f.x) + 0x8000u;
                uint32_t u1 = __float_as_uint(f.y) + 0x8000u;
                uint32_t u2 = __float_as_uint(f.z) + 0x8000u;
                uint32_t u3 = __float_as_uint(f.w) + 0x8000u;
                d[2 * j]     = __builtin_amdgcn_perm(u1, u0, 0x07060302);
                d[2 * j + 1] = __builtin_amdgcn_perm(u3, u2, 0x07060302);
            }
            *(u32x4*)&A_lds[arow * GST + acb]     = (u32x4){d[0], d[1], d[2], d[3]};
            *(u32x4*)&A_lds[arow * GST + acb + 8] = (u32x4){d[4], d[5], d[6], d[7]};
        }
        {
            const uint16_t* wp = Wp + (size_t)wrow * C_ + k0 + wcb;
#pragma unroll
            for (int i = 0; i < 4; i++)
                *(us8*)&W_lds[wrow * GST + wcb + i * 8] = *(const us8*)(wp + i * 8);
        }
        __syncthreads();

#pragma unroll
        for (int kc = 0; kc < 2; kc++) {
            bf16x8 af[2];
#pragma unroll
            for (int mf = 0; mf < 2; mf++)
                af[mf] = *(const bf16x8*)&A_lds[(wm * 32 + mf * 16 + lx) * GST + kc * 32 + quad * 8];
#pragma unroll
            for (int nf = 0; nf < 4; nf++) {
                bf16x8 bf = *(const bf16x8*)&W_lds[(wn * 64 + nf * 16 + lx) * GST + kc * 32 + quad * 8];
                acc[0][nf] = __builtin_amdgcn_mfma_f32_16x16x32_bf16(af[0], bf, acc[0][nf], 0, 0, 0);
                acc[1][nf] = __builtin_amdgcn_mfma_f32_16x16x32_bf16(af[1], bf, acc[1][nf], 0, 0, 0);
            }
        }
        __syncthreads();
    }

    int mrow0 = m0 + wm * 32 + quad * 4;
    if (wsel == 2) {
#pragma unroll
        for (int mf = 0; mf < 2; mf++) {
            int mbase = mrow0 + mf * 16;
            int batch = mbase >> 12;
            int t     = mbase & 4095;
#pragma unroll
            for (int nf = 0; nf < 4; nf++) {
                int n = wn * 64 + nf * 16 + lx;
                us4 pv;
#pragma unroll
                for (int r = 0; r < 4; r++) pv[r] = bfru(acc[mf][nf][r]);
                *(us4*)&vT[(size_t)batch * D_ * T_ + (size_t)n * T_ + t] = pv;
            }
        }
    } else {
        uint16_t* dst = (wsel == 0) ? qb : kb;
        float sc = (wsel == 0) ? QSCALE : 1.0f;
#pragma unroll
        for (int mf = 0; mf < 2; mf++)
#pragma unroll
            for (int nf = 0; nf < 4; nf++) {
                int n = wn * 64 + nf * 16 + lx;
#pragma unroll
                for (int r = 0; r < 4; r++)
                    dst[(size_t)(mrow0 + mf * 16 + r) * D_ + n] = bfru(acc[mf][nf][r] * sc);
            }
    }
}

// ---------------------------------------------------------------------------
// Kernel 3: split-K flash attention. 128 Q-rows/block (4 waves x 32 rows,
// 2 row-frags/wave -> each K/V LDS read feeds 2 MFMAs; V reads shared by both
// row-frags). Fixed-base softmax. XOR-swizzled LDS, 48 KB -> 3 blocks/CU.
// Chunks of <=4 key-tiles(64); grid = 4 x 272 = 1088 blocks, longest-first.
// ---------------------------------------------------------------------------
__global__ __launch_bounds__(256, 3) void attn(const uint16_t* __restrict__ qb,
                                               const uint16_t* __restrict__ kb,
                                               const uint16_t* __restrict__ vT,
                                               uint16_t* __restrict__ part,
                                               float* __restrict__ ml) {
    __shared__ __align__(16) uint16_t K_lds[64 * 128];     // 16384 B
    __shared__ __align__(16) uint16_t V_lds[128 * 64];     // 16384 B
    __shared__ __align__(16) uint16_t P_lds[4 * 32 * 64];  // 16384 B

    int tid  = threadIdx.x;
    int lane = tid & 63;
    int wave = tid >> 6;
    int quad = lane >> 4;
    int lx   = lane & 15;
    int lx7  = lx & 7;

    // decode blockIdx -> (batch, logical chunk L), longest chunks first
    int batch = blockIdx.x & 3;
    int L     = NCHUNK_PB - 1 - (blockIdx.x >> 2);
    int m = 0;
    while (m < 15 && (m + 1) * (m + 2) <= L) m++;
    int jt2, chunk;
    if (L >= (m + 1) * (m + 1)) { jt2 = 2 * m + 1; chunk = L - (m + 1) * (m + 1); }
    else                        { jt2 = 2 * m;     chunk = L - m * (m + 1); }
    int lidx = batch * NCHUNK_PB + L;

    int q0     = jt2 * 128;
    int st0    = chunk * 4;
    int ntiles = min(4, 2 * jt2 + 2 - st0);
    int wrow0  = q0 + wave * 32;

    // Q fragments: 32 rows x 128 d per wave (2 row-frags), 32 VGPRs
    bf16x8 qf[2][4];
#pragma unroll
    for (int mf = 0; mf < 2; mf++) {
        const uint16_t* qp = qb + (size_t)(batch * T_ + wrow0 + mf * 16 + lx) * D_ + quad * 8;
#pragma unroll
        for (int kc = 0; kc < 4; kc++) qf[mf][kc] = *(const bf16x8*)(qp + kc * 32);
    }

    f32x4 o[2][8];
#pragma unroll
    for (int mf = 0; mf < 2; mf++)
#pragma unroll
        for (int i = 0; i < 8; i++) o[mf][i] = (f32x4){0.f, 0.f, 0.f, 0.f};
    float l_i[2][4] = {{0.f, 0.f, 0.f, 0.f}, {0.f, 0.f, 0.f, 0.f}};

    int krow = tid >> 2, kc0 = (tid & 3) * 4;  // K: 4 chunks(16B)/thread
    int vd   = tid >> 1, vc0 = (tid & 1) * 4;  // V: 4 chunks/thread

    for (int it = 0; it < ntiles; it++) {
        int s0 = (st0 + it) * 64;
        {
            const uint16_t* kp = kb + (size_t)(batch * T_ + s0 + krow) * D_ + kc0 * 8;
#pragma unroll
            for (int i = 0; i < 4; i++)
                *(us8*)&K_lds[krow * 128 + (((kc0 + i) ^ (krow & 7)) * 8)] = *(const us8*)(kp + i * 8);
        }
        {
            const uint16_t* vp = vT + (size_t)batch * D_ * T_ + (size_t)vd * T_ + s0 + vc0 * 8;
#pragma unroll
            for (int i = 0; i < 4; i++)
                *(us8*)&V_lds[vd * 64 + (((vc0 + i) ^ (vd & 7)) * 8)] = *(const us8*)(vp + i * 8);
        }
        __syncthreads();

        // waves whose 32 rows lie entirely above this key tile skip compute
        if (s0 <= wrow0 + 31) {
#pragma unroll
            for (int mf = 0; mf < 2; mf++) {
                f32x4 s[4];
                for (int nf = 0; nf < 4; nf++) s[nf] = (f32x4){0.f, 0.f, 0.f, 0.f};
#pragma unroll
                for (int kc = 0; kc < 4; kc++)
#pragma unroll
                    for (int nf = 0; nf < 4; nf++) {
                        bf16x8 kf = *(const bf16x8*)&K_lds[(nf * 16 + lx) * 128 + (((kc * 4 + quad) ^ lx7) * 8)];
                        s[nf] = __builtin_amdgcn_mfma_f32_16x16x32_bf16(qf[mf][kc], kf, s[nf], 0, 0, 0);
                    }

                int  rowg     = wrow0 + mf * 16 + quad * 4;
                bool needmask = (s0 + 63 > wrow0 + mf * 16);
#pragma unroll
                for (int nf = 0; nf < 4; nf++) {
                    int colg = s0 + nf * 16 + lx;
#pragma unroll
                    for (int r = 0; r < 4; r++) {
                        float sv = s[nf][r];
                        if (needmask && (colg > rowg + r)) sv = -INFINITY;
                        float e = exp2f(sv - M0);
                        l_i[mf][r] += e;
                        int prow = mf * 16 + quad * 4 + r;
                        int c    = nf * 2 + (lx >> 3);
                        P_lds[wave * 2048 + prow * 64 + ((c ^ (prow & 7)) * 8) + lx7] = bfru(e);
                    }
                }
            }

            // PV: A = P (per-wave), B = V^T; vf reads shared by both row-frags
            bf16x8 pf[2][2];
#pragma unroll
            for (int mf = 0; mf < 2; mf++)
#pragma unroll
                for (int kc = 0; kc < 2; kc++)
                    pf[mf][kc] = *(const bf16x8*)&P_lds[wave * 2048 + (mf * 16 + lx) * 64 + (((kc * 4 + quad) ^ lx7) * 8)];
#pragma unroll
            for (int nf2 = 0; nf2 < 8; nf2++)
#pragma unroll
                for (int kc = 0; kc < 2; kc++) {
                    bf16x8 vf = *(const bf16x8*)&V_lds[(nf2 * 16 + lx) * 64 + (((kc * 4 + quad) ^ lx7) * 8)];
                    o[0][nf2] = __builtin_amdgcn_mfma_f32_16x16x32_bf16(pf[0][kc], vf, o[0][nf2], 0, 0, 0);
                    o[1][nf2] = __builtin_amdgcn_mfma_f32_16x16x32_bf16(pf[1][kc], vf, o[1][nf2], 0, 0, 0);
                }
        }
        __syncthreads();
    }

    // reduce l across 16 lanes (once per kernel)
#pragma unroll
    for (int off = 1; off < 16; off <<= 1)
#pragma unroll
        for (int mf = 0; mf < 2; mf++)
#pragma unroll
            for (int r = 0; r < 4; r++)
                l_i[mf][r] += __shfl_xor(l_i[mf][r], off, 64);

    // write unnormalized partial (bf16) + l at the LOGICAL index
    uint16_t* pp = part + (size_t)lidx * (128 * 128);
#pragma unroll
    for (int mf = 0; mf < 2; mf++)
#pragma unroll
        for (int nf2 = 0; nf2 < 8; nf2++)
#pragma unroll
            for (int r = 0; r < 4; r++) {
                int lrow = wave * 32 + mf * 16 + quad * 4 + r;
                pp[lrow * 128 + nf2 * 16 + lx] = bfru(o[mf][nf2][r]);
            }
    if (lx == 0) {
#pragma unroll
        for (int mf = 0; mf < 2; mf++)
#pragma unroll
            for (int r = 0; r < 4; r++)
                ml[(size_t)lidx * 128 + wave * 32 + mf * 16 + quad * 4 + r] = l_i[mf][r];
    }
}

// ---------------------------------------------------------------------------
// Kernel 4: combine split-K partials: plain sums (fixed M0 cancels).
// Block = (batch, 128-row q-tile); 256 threads, 2 threads/row.
// ---------------------------------------------------------------------------
__global__ __launch_bounds__(256) void combine(const uint16_t* __restrict__ part,
                                               const float* __restrict__ ml,
                                               float* __restrict__ out) {
    int bidx  = blockIdx.x;
    int batch = bidx >> 5;
    int jt2   = bidx & 31;
    int h     = jt2 >> 1;
    int base  = batch * NCHUNK_PB + ((jt2 & 1) ? (h + 1) * (h + 1) : h * (h + 1));
    int nch   = (jt2 + 2) >> 1;

    int tid  = threadIdx.x;
    int lrow = tid >> 1;
    int c0   = (tid & 1) * 64;

    float Lsum = 0.f;
    f32x4 acc[16];
#pragma unroll
    for (int i = 0; i < 16; i++) acc[i] = (f32x4){0.f, 0.f, 0.f, 0.f};

    for (int c = 0; c < nch; c++) {
        Lsum += ml[(size_t)(base + c) * 128 + lrow];
        const uint16_t* p = part + (size_t)(base + c) * (128 * 128) + lrow * 128 + c0;
#pragma unroll
        for (int i = 0; i < 8; i++) {
            us8 v = *(const us8*)(p + i * 8);
#pragma unroll
            for (int j = 0; j < 8; j++)
                acc[i * 2 + (j >> 2)][j & 3] += bf2f(v[j]);
        }
    }
    float inv = 1.f / Lsum;
    size_t row = (size_t)(batch * T_ + jt2 * 128 + lrow);
#pragma unroll
    for (int i = 0; i < 16; i++)
        *(f32x4*)(out + row * 128 + c0 + i * 4) = acc[i] * inv;
}

// ---------------------------------------------------------------------------
extern "C" void kernel_launch(void* const* d_in, const int* in_sizes, int n_in,
                              void* d_out, int out_size, void* d_ws, size_t ws_size,
                              hipStream_t stream) {
    const float* x  = (const float*)d_in[0];
    const float* Wq = (const float*)d_in[1];
    const float* Wk = (const float*)d_in[2];
    const float* Wv = (const float*)d_in[3];
    float* out = (float*)d_out;

    uint16_t* ws = (uint16_t*)d_ws;
    uint16_t* qb = ws;                                   // 16384*128 bf16
    uint16_t* kb = qb + (size_t)16384 * 128;
    uint16_t* vT = kb + (size_t)16384 * 128;
    uint16_t* WT = vT + (size_t)16384 * 128;             // 3*128*1024
    uint16_t* part = WT + (size_t)3 * D_ * C_;           // 1088*128*128 bf16
    float* ml = (float*)(part + (size_t)4 * NCHUNK_PB * 128 * 128);  // 1088*128 fp32

    prep_w<<<dim3((3 * D_ * C_ + 255) / 256), dim3(256), 0, stream>>>(Wq, Wk, Wv, WT);
    qkv_gemm<<<dim3(3 * (16384 / 64)), dim3(256), 0, stream>>>(x, WT, qb, kb, vT);
    attn<<<dim3(B_ * NCHUNK_PB), dim3(256), 0, stream>>>(qb, kb, vT, part, ml);
    combine<<<dim3(B_ * (T_ / 128)), dim3(256), 0, stream>>>(part, ml, out);
}